// Round 11
// baseline (492.778 us; speedup 1.0000x reference)
//
#include <hip/hip_runtime.h>
#include <hip/hip_bf16.h>

// Device buffers are FLOAT32 (confirmed R4/R5). bf16 MFMA compute, f32 accum.
// R10->R11: attention occupancy fix. Each (head, qtile-pair) unit now runs as
// TWO waves in one block, splitting KV tiles by parity (kt/64 mod 2 == wid),
// merged in-block via LDS flash-merge (no global partials — R9's mistake).
// 2048 waves = 2/SIMD. K/V traffic unchanged (each kt read once per unit).

typedef __attribute__((ext_vector_type(8))) short short8_t;
typedef __attribute__((ext_vector_type(2))) unsigned uint2_t;
typedef __attribute__((ext_vector_type(8))) __bf16 bf16x8;
typedef __attribute__((ext_vector_type(4))) float f32x4;
typedef __attribute__((ext_vector_type(16))) float f32x16;

#define SEQLEN 2048
#define QSCALE 0.08838834764831845f   // HEAD_DIM^-0.5, folded into Q at RoPE

__device__ __forceinline__ short f2b(float f) {
  if (!__builtin_isfinite(f)) f = 0.0f;   // diagnostic scrub (final stores only)
  union { float f; unsigned u; } v; v.f = f;
  unsigned r = (v.u + 0x7fffu + ((v.u >> 16) & 1u)) >> 16;  // RNE
  return (short)r;
}
__device__ __forceinline__ float sf(float f) {
  return __builtin_isfinite(f) ? f : 0.0f;
}
__device__ __forceinline__ short8_t cvt8(const float* p) {
  f32x4 a = *(const f32x4*)p;
  f32x4 b = *(const f32x4*)(p + 4);
  short8_t o;
  o[0] = f2b(a[0]); o[1] = f2b(a[1]); o[2] = f2b(a[2]); o[3] = f2b(a[3]);
  o[4] = f2b(b[0]); o[5] = f2b(b[1]); o[6] = f2b(b[2]); o[7] = f2b(b[3]);
  return o;
}
// pack two f32 -> (bf16 hi<<16 | bf16 lo); inputs finite by construction
__device__ __forceinline__ unsigned pkb(float lo, float hi) {
  union { float f; unsigned u; } a, b; a.f = lo; b.f = hi;
  unsigned ra = (a.u + 0x7fffu + ((a.u >> 16) & 1u)) >> 16;
  unsigned rb = (b.u + 0x7fffu + ((b.u >> 16) & 1u)) & 0xffff0000u;
  return rb | ra;
}

#define GLD16(gp, lp) __builtin_amdgcn_global_load_lds( \
    (const __attribute__((address_space(1))) void*)(gp), \
    (__attribute__((address_space(3))) void*)(lp), 16, 0, 0)

// ---------------------------------------------------------------------------
__global__ __launch_bounds__(256) void cvt_bf16(
    const float* __restrict__ in, short* __restrict__ out)
{
  size_t i = ((size_t)blockIdx.x * 256 + threadIdx.x) * 8;
  *(short8_t*)&out[i] = cvt8(in + i);
}

// ---------------------------------------------------------------------------
// GEMM: C[m][n] = sum_k A[m][k]*W[n][k], A/W bf16, C f32. m97 structure.
// ---------------------------------------------------------------------------
__global__ __launch_bounds__(256) void gemm_bf(
    const short* __restrict__ A, const short* __restrict__ W,
    float* __restrict__ C1, float* __restrict__ C2,
    int K, int ldc, int splitN)
{
  __shared__ short As[128 * 64];
  __shared__ short Ws[128 * 64];
  const int tid  = threadIdx.x;
  const int lane = tid & 63;
  const int wid  = tid >> 6;
  const int l15  = lane & 15;
  const int l4   = lane >> 4;

  const int nwg = (int)(gridDim.x * gridDim.y);
  int bid = (int)(blockIdx.y * gridDim.x + blockIdx.x);
  int swz = (bid & 7) * (nwg >> 3) + (bid >> 3);
  const int m0 = (swz / (int)gridDim.x) * 128;
  const int n0 = (swz % (int)gridDim.x) * 128;

  const int wr = (wid >> 1) * 64;
  const int wc = (wid & 1) * 64;
  const int srow = tid >> 3;
  const int scol = (tid & 7) * 8;

  f32x4 acc[4][4] = {};

  const short* Ab = A + (size_t)(m0 + srow) * K + scol;
  const short* Wb = W + (size_t)(n0 + srow) * K + scol;

  for (int k0 = 0; k0 < K; k0 += 64) {
#pragma unroll
    for (int i = 0; i < 4; ++i) {
      GLD16(Ab + (size_t)(i * 32) * K + k0, &As[(i * 32 + wid * 8) * 64]);
      GLD16(Wb + (size_t)(i * 32) * K + k0, &Ws[(i * 32 + wid * 8) * 64]);
    }
    __syncthreads();

#pragma unroll
    for (int kk = 0; kk < 2; ++kk) {
      bf16x8 af[4], wf[4];
#pragma unroll
      for (int m = 0; m < 4; ++m)
        af[m] = *(const bf16x8*)&As[(wr + m * 16 + l15) * 64 + kk * 32 + l4 * 8];
#pragma unroll
      for (int n = 0; n < 4; ++n)
        wf[n] = *(const bf16x8*)&Ws[(wc + n * 16 + l15) * 64 + kk * 32 + l4 * 8];
#pragma unroll
      for (int m = 0; m < 4; ++m)
#pragma unroll
        for (int n = 0; n < 4; ++n)
          acc[m][n] = __builtin_amdgcn_mfma_f32_16x16x32_bf16(af[m], wf[n], acc[m][n], 0, 0, 0);
    }
    __syncthreads();
  }

  float* Cb = (n0 < splitN) ? C1 : (C2 - splitN);
#pragma unroll
  for (int m = 0; m < 4; ++m) {
    int rbase = m0 + wr + m * 16 + l4 * 4;
#pragma unroll
    for (int n = 0; n < 4; ++n) {
      int cbase = n0 + wc + n * 16 + l15;
#pragma unroll
      for (int r = 0; r < 4; ++r)
        Cb[(size_t)(rbase + r) * ldc + cbase] = sf(acc[m][n][r]);
    }
  }
}

// ---------------------------------------------------------------------------
// RoPE
// ---------------------------------------------------------------------------
__device__ __forceinline__ void rope8(const float* in, float* out,
                                      const float* fc, const float* fs, int t, int p0)
{
  f32x4 a = *(const f32x4*)in;
  f32x4 b = *(const f32x4*)(in + 4);
  f32x4 cv = *(const f32x4*)&fc[t * 64 + p0];
  f32x4 sv = *(const f32x4*)&fs[t * 64 + p0];
  float x0[8] = {a[0], a[1], a[2], a[3], b[0], b[1], b[2], b[3]};
#pragma unroll
  for (int i = 0; i < 4; ++i) {
    float xr = x0[2 * i], xi = x0[2 * i + 1];
    out[2 * i]     = sf(xr * cv[i] - xi * sv[i]);
    out[2 * i + 1] = sf(xr * sv[i] + xi * cv[i]);
  }
}

__global__ __launch_bounds__(256) void rope_q_bf(
    const float* __restrict__ q, short* __restrict__ qb,
    const float* __restrict__ fc, const float* __restrict__ fs)
{
  size_t idx = ((size_t)blockIdx.x * 256 + threadIdx.x) * 8;
  int t   = (int)(idx >> 12);
  int col = (int)(idx & 4095);
  float o[8];
  rope8(&q[idx], o, fc, fs, t, (col & 127) >> 1);
  short8_t ob;
#pragma unroll
  for (int i = 0; i < 8; ++i) ob[i] = f2b(o[i] * QSCALE);
  *(short8_t*)&qb[idx] = ob;
}

__global__ __launch_bounds__(256) void rope_k_dual(
    float* __restrict__ ck, short* __restrict__ kb,
    const float* __restrict__ fc, const float* __restrict__ fs)
{
  size_t idx = ((size_t)blockIdx.x * 256 + threadIdx.x) * 8;
  int t   = (int)(idx >> 10);
  int col = (int)(idx & 1023);
  float o[8];
  rope8(&ck[idx], o, fc, fs, t, (col & 127) >> 1);
  *(f32x4*)&ck[idx]     = f32x4{o[0], o[1], o[2], o[3]};
  *(f32x4*)&ck[idx + 4] = f32x4{o[4], o[5], o[6], o[7]};
  short8_t ob;
#pragma unroll
  for (int i = 0; i < 8; ++i) ob[i] = f2b(o[i]);
  *(short8_t*)&kb[idx] = ob;
}

// cache_v f32 [2048][8*128] -> Vt bf16 [8][128][2048]
__global__ __launch_bounds__(256) void transpose_v(
    const float* __restrict__ cv, short* __restrict__ Vt)
{
  __shared__ short tile[64][72];
  const int t0 = blockIdx.x * 64;
  const int d0 = blockIdx.y * 64;
  const int h  = blockIdx.z;
  const int tid = threadIdx.x;
  const int r = tid >> 3;
  const int c = (tid & 7) * 8;
#pragma unroll
  for (int it = 0; it < 2; ++it) {
    short8_t v = cvt8(&cv[(size_t)(t0 + it * 32 + r) * 1024 + h * 128 + d0 + c]);
    *(short8_t*)&tile[it * 32 + r][c] = v;
  }
  __syncthreads();
#pragma unroll
  for (int it = 0; it < 2; ++it) {
    int dr = it * 32 + r;
    short8_t v;
#pragma unroll
    for (int i = 0; i < 8; ++i) v[i] = tile[c + i][dr];
    *(short8_t*)&Vt[(size_t)(h * 128 + d0 + dr) * SEQLEN + t0 + c] = v;
  }
}

// ---------------------------------------------------------------------------
// Causal flash attention, swapped-QK^T 32x32. One block = one (head, pair)
// unit = TWO waves splitting KV tiles by parity, LDS flash-merge at end.
// Grid 1024 x 128 thr: bid&7 = kvh (XCD pin), j=bid>>3: h=kvh*4+(j&3), i=j>>2.
// Tiles: A = qtile 63-i, B = qtile i (B masked off once kt passes kendB).
// Lane state: q = lane&31, S^T keys = crow(r,hi) = (r&3)+8*(r>>2)+4*hi.
// ---------------------------------------------------------------------------
__global__ __launch_bounds__(128, 2) void attn_fwd4(
    const short* __restrict__ Q,    // [2048][4096] bf16, pre-scaled
    const short* __restrict__ Kc,   // [2048][1024] bf16
    const short* __restrict__ Vt,   // [8][128][2048] bf16
    short* __restrict__ O)          // [2048][4096] bf16
{
  const int bid = (int)blockIdx.x;
  const int kvh = bid & 7;
  const int j   = bid >> 3;
  const int h   = kvh * 4 + (j & 3);
  const int i   = j >> 2;               // 0..31
  const int qtA = 63 - i, qtB = i;
  const int tid = (int)threadIdx.x;
  const int wid = tid >> 6;             // 0,1 = KV parity
  const int lane = tid & 63;
  const int l31 = lane & 31;
  const int hi  = lane >> 5;

  __shared__ short PA[2][32][88], PB[2][32][88];   // per-wave P staging
  __shared__ float oxch[16][64];                   // merge staging (4 KB)
  __shared__ float mlx[2][2][32][2];               // [wid][tile][q][{m,l}]
  __shared__ float scx[2][2][32];                  // normalized scales
  __shared__ float rexch[2][64];                   // per-wave rescale bcast

  const int q0A = qtA * 32, q0B = qtB * 32;
  const int qgA = q0A + l31, qgB = q0B + l31;
  const int kendA = q0A + 32, kendB = q0B + 32;

  bf16x8 qfA[8], qfB[8];
  {
    const short* qpA = Q + (size_t)qgA * 4096 + h * 128 + hi * 8;
    const short* qpB = Q + (size_t)qgB * 4096 + h * 128 + hi * 8;
#pragma unroll
    for (int ks = 0; ks < 8; ++ks) {
      qfA[ks] = *(const bf16x8*)(qpA + ks * 16);
      qfB[ks] = *(const bf16x8*)(qpB + ks * 16);
    }
  }

  f32x16 oA0 = {}, oA1 = {}, oA2 = {}, oA3 = {};
  f32x16 oB0 = {}, oB1 = {}, oB2 = {}, oB3 = {};
  float mA = -1e30f, lA = 0.f, mB = -1e30f, lB = 0.f;

  for (int kt = wid * 64; kt < kendA; kt += 128) {
    const bool actB = (kt < kendB);     // wave-uniform
    f32x16 sA0 = {}, sA1 = {}, sB0 = {}, sB1 = {};
    {
      const short* kp = Kc + (size_t)(kt + l31) * 1024 + kvh * 128 + hi * 8;
      __builtin_amdgcn_s_setprio(1);
      if (actB) {
#pragma unroll
        for (int ks = 0; ks < 8; ++ks) {
          bf16x8 k0 = *(const bf16x8*)(kp + ks * 16);
          bf16x8 k1 = *(const bf16x8*)(kp + 32 * 1024 + ks * 16);
          sA0 = __builtin_amdgcn_mfma_f32_32x32x16_bf16(k0, qfA[ks], sA0, 0, 0, 0);
          sA1 = __builtin_amdgcn_mfma_f32_32x32x16_bf16(k1, qfA[ks], sA1, 0, 0, 0);
          sB0 = __builtin_amdgcn_mfma_f32_32x32x16_bf16(k0, qfB[ks], sB0, 0, 0, 0);
          sB1 = __builtin_amdgcn_mfma_f32_32x32x16_bf16(k1, qfB[ks], sB1, 0, 0, 0);
        }
      } else {
#pragma unroll
        for (int ks = 0; ks < 8; ++ks) {
          bf16x8 k0 = *(const bf16x8*)(kp + ks * 16);
          bf16x8 k1 = *(const bf16x8*)(kp + 32 * 1024 + ks * 16);
          sA0 = __builtin_amdgcn_mfma_f32_32x32x16_bf16(k0, qfA[ks], sA0, 0, 0, 0);
          sA1 = __builtin_amdgcn_mfma_f32_32x32x16_bf16(k1, qfA[ks], sA1, 0, 0, 0);
        }
      }
      __builtin_amdgcn_s_setprio(0);
    }

    // ----- tile A softmax -----
    if (kt + 63 > q0A) {
#pragma unroll
      for (int r = 0; r < 16; ++r) {
        int crow = (r & 3) + 8 * (r >> 2) + 4 * hi;
        if (kt + crow > qgA)      sA0[r] = -1e30f;
        if (kt + 32 + crow > qgA) sA1[r] = -1e30f;
      }
    }
    {
      float t[8];
#pragma unroll
      for (int r = 0; r < 8; ++r)
        t[r] = fmaxf(fmaxf(sA0[r], sA0[r + 8]), fmaxf(sA1[r], sA1[r + 8]));
      float pmax = fmaxf(fmaxf(fmaxf(t[0], t[1]), fmaxf(t[2], t[3])),
                         fmaxf(fmaxf(t[4], t[5]), fmaxf(t[6], t[7])));
      pmax = fmaxf(pmax, __shfl_xor(pmax, 32, 64));
      if (!__all(pmax <= mA + 8.f)) {
        float mnew = fmaxf(mA, pmax);
        float resc = __expf(mA - mnew);
        mA = mnew; lA *= resc;
        if (lane < 32) rexch[wid][l31] = resc;
#pragma unroll
        for (int r = 0; r < 16; ++r) {
          float rs = rexch[wid][(r & 3) + 8 * (r >> 2) + 4 * hi];
          oA0[r] *= rs; oA1[r] *= rs; oA2[r] *= rs; oA3[r] *= rs;
        }
      }
      float psum = 0.f;
#pragma unroll
      for (int r = 0; r < 16; ++r) { sA0[r] = __expf(sA0[r] - mA); psum += sA0[r]; }
#pragma unroll
      for (int r = 0; r < 16; ++r) { sA1[r] = __expf(sA1[r] - mA); psum += sA1[r]; }
      lA += psum + __shfl_xor(psum, 32, 64);
#pragma unroll
      for (int t4 = 0; t4 < 4; ++t4) {
        int c = 8 * t4 + 4 * hi;
        *(uint2_t*)&PA[wid][l31][c]      = uint2_t{pkb(sA0[4*t4], sA0[4*t4+1]), pkb(sA0[4*t4+2], sA0[4*t4+3])};
        *(uint2_t*)&PA[wid][l31][32 + c] = uint2_t{pkb(sA1[4*t4], sA1[4*t4+1]), pkb(sA1[4*t4+2], sA1[4*t4+3])};
      }
    }

    // ----- tile B softmax -----
    if (actB) {
      if (kt + 63 > q0B) {
#pragma unroll
        for (int r = 0; r < 16; ++r) {
          int crow = (r & 3) + 8 * (r >> 2) + 4 * hi;
          if (kt + crow > qgB)      sB0[r] = -1e30f;
          if (kt + 32 + crow > qgB) sB1[r] = -1e30f;
        }
      }
      float t[8];
#pragma unroll
      for (int r = 0; r < 8; ++r)
        t[r] = fmaxf(fmaxf(sB0[r], sB0[r + 8]), fmaxf(sB1[r], sB1[r + 8]));
      float pmax = fmaxf(fmaxf(fmaxf(t[0], t[1]), fmaxf(t[2], t[3])),
                         fmaxf(fmaxf(t[4], t[5]), fmaxf(t[6], t[7])));
      pmax = fmaxf(pmax, __shfl_xor(pmax, 32, 64));
      if (!__all(pmax <= mB + 8.f)) {
        float mnew = fmaxf(mB, pmax);
        float resc = __expf(mB - mnew);
        mB = mnew; lB *= resc;
        if (lane < 32) rexch[wid][32 + l31] = resc;
#pragma unroll
        for (int r = 0; r < 16; ++r) {
          float rs = rexch[wid][32 + (r & 3) + 8 * (r >> 2) + 4 * hi];
          oB0[r] *= rs; oB1[r] *= rs; oB2[r] *= rs; oB3[r] *= rs;
        }
      }
      float psum = 0.f;
#pragma unroll
      for (int r = 0; r < 16; ++r) { sB0[r] = __expf(sB0[r] - mB); psum += sB0[r]; }
#pragma unroll
      for (int r = 0; r < 16; ++r) { sB1[r] = __expf(sB1[r] - mB); psum += sB1[r]; }
      lB += psum + __shfl_xor(psum, 32, 64);
#pragma unroll
      for (int t4 = 0; t4 < 4; ++t4) {
        int c = 8 * t4 + 4 * hi;
        *(uint2_t*)&PB[wid][l31][c]      = uint2_t{pkb(sB0[4*t4], sB0[4*t4+1]), pkb(sB0[4*t4+2], sB0[4*t4+3])};
        *(uint2_t*)&PB[wid][l31][32 + c] = uint2_t{pkb(sB1[4*t4], sB1[4*t4+1]), pkb(sB1[4*t4+2], sB1[4*t4+3])};
      }
    }

    // ----- PV (V-frags loaded once, used by A and B) -----
    const short* vb = Vt + (size_t)(kvh * 128 + l31) * SEQLEN + kt + hi * 8;
#pragma unroll
    for (int g = 0; g < 4; ++g) {
      const short* vg = vb + g * 16;
      bf16x8 vf0 = *(const bf16x8*)(vg);
      bf16x8 vf1 = *(const bf16x8*)(vg + 32 * SEQLEN);
      bf16x8 vf2 = *(const bf16x8*)(vg + 64 * SEQLEN);
      bf16x8 vf3 = *(const bf16x8*)(vg + (size_t)96 * SEQLEN);
      bf16x8 pfA = *(const bf16x8*)&PA[wid][l31][g * 16 + hi * 8];
      __builtin_amdgcn_s_setprio(1);
      oA0 = __builtin_amdgcn_mfma_f32_32x32x16_bf16(pfA, vf0, oA0, 0, 0, 0);
      oA1 = __builtin_amdgcn_mfma_f32_32x32x16_bf16(pfA, vf1, oA1, 0, 0, 0);
      oA2 = __builtin_amdgcn_mfma_f32_32x32x16_bf16(pfA, vf2, oA2, 0, 0, 0);
      oA3 = __builtin_amdgcn_mfma_f32_32x32x16_bf16(pfA, vf3, oA3, 0, 0, 0);
      if (actB) {
        bf16x8 pfB = *(const bf16x8*)&PB[wid][l31][g * 16 + hi * 8];
        oB0 = __builtin_amdgcn_mfma_f32_32x32x16_bf16(pfB, vf0, oB0, 0, 0, 0);
        oB1 = __builtin_amdgcn_mfma_f32_32x32x16_bf16(pfB, vf1, oB1, 0, 0, 0);
        oB2 = __builtin_amdgcn_mfma_f32_32x32x16_bf16(pfB, vf2, oB2, 0, 0, 0);
        oB3 = __builtin_amdgcn_mfma_f32_32x32x16_bf16(pfB, vf3, oB3, 0, 0, 0);
      }
      __builtin_amdgcn_s_setprio(0);
    }
  }

  // ----- in-block flash merge of the two KV halves -----
  if (lane < 32) {
    mlx[wid][0][l31][0] = mA; mlx[wid][0][l31][1] = lA;
    mlx[wid][1][l31][0] = mB; mlx[wid][1][l31][1] = lB;
  }
  __syncthreads();
  if (wid == 0 && lane < 32) {
#pragma unroll
    for (int T = 0; T < 2; ++T) {
      float m0 = mlx[0][T][l31][0], l0 = mlx[0][T][l31][1];
      float m1 = mlx[1][T][l31][0], l1 = mlx[1][T][l31][1];
      float M  = fmaxf(m0, m1);
      float e0 = __expf(m0 - M), e1 = __expf(m1 - M);
      float den = l0 * e0 + l1 * e1;
      scx[0][T][l31] = e0 / den;
      scx[1][T][l31] = e1 / den;
    }
  }
  __syncthreads();

#define MERGE_STORE(oreg, T, q0, g) do {                                     \
    if (wid == 1) {                                                          \
      _Pragma("unroll")                                                      \
      for (int r = 0; r < 16; ++r)                                           \
        oxch[r][lane] = (oreg)[r] * scx[1][T][(r & 3) + 8 * (r >> 2) + 4 * hi]; \
    }                                                                        \
    __syncthreads();                                                         \
    if (wid == 0) {                                                          \
      _Pragma("unroll")                                                      \
      for (int r = 0; r < 16; ++r) {                                         \
        int crow = (r & 3) + 8 * (r >> 2) + 4 * hi;                          \
        float v = (oreg)[r] * scx[0][T][crow] + oxch[r][lane];               \
        O[(size_t)((q0) + crow) * 4096 + h * 128 + (g) * 32 + l31] = f2b(v); \
      }                                                                      \
    }                                                                        \
    __syncthreads();                                                         \
  } while (0)

  MERGE_STORE(oA0, 0, q0A, 0);
  MERGE_STORE(oA1, 0, q0A, 1);
  MERGE_STORE(oA2, 0, q0A, 2);
  MERGE_STORE(oA3, 0, q0A, 3);
  MERGE_STORE(oB0, 1, q0B, 0);
  MERGE_STORE(oB1, 1, q0B, 1);
  MERGE_STORE(oB2, 1, q0B, 2);
  MERGE_STORE(oB3, 1, q0B, 3);
#undef MERGE_STORE
}

// ---------------------------------------------------------------------------
extern "C" void kernel_launch(void* const* d_in, const int* in_sizes, int n_in,
                              void* d_out, int out_size, void* d_ws, size_t ws_size,
                              hipStream_t stream) {
  const float* x  = (const float*)d_in[0];
  const float* wq = (const float*)d_in[1];
  const float* wk = (const float*)d_in[2];
  const float* wv = (const float*)d_in[3];
  const float* wo = (const float*)d_in[4];
  const float* fc = (const float*)d_in[5];
  const float* fs = (const float*)d_in[6];

  float* out = (float*)d_out;
  float* out_main = out;                               // [2048][4096]
  float* cache_k  = out + (size_t)2048 * 4096;         // [4096][8][128]
  float* cache_v  = cache_k + (size_t)4096 * 8 * 128;  // [4096][8][128]

  const size_t MB_W = 33554432;   // 4096x4096 bf16
  const size_t MB_X = 16777216;   // 2048x4096 bf16
  short* slotA = (short*)d_ws;
  short* x_bf  = (short*)((char*)d_ws + MB_W);
  short* attn_out = x_bf;
  short* Vt    = (short*)((char*)d_ws + MB_W + MB_X);
  short* q_bf  = slotA;
  short* k_bf  = slotA + (size_t)2048 * 4096;

  // converts + projections
  cvt_bf16<<<4096, 256, 0, stream>>>(x, x_bf);
  cvt_bf16<<<8192, 256, 0, stream>>>(wq, slotA);
  gemm_bf<<<dim3(32, 16), 256, 0, stream>>>(x_bf, slotA, out_main, out_main, 4096, 4096, 1 << 30);
  cvt_bf16<<<2048, 256, 0, stream>>>(wk, slotA);
  cvt_bf16<<<2048, 256, 0, stream>>>(wv, slotA + (size_t)1024 * 4096);
  gemm_bf<<<dim3(16, 16), 256, 0, stream>>>(x_bf, slotA, cache_k, cache_v, 4096, 1024, 1024);

  // RoPE + V transpose + cache tail zeros
  rope_q_bf<<<4096, 256, 0, stream>>>(out_main, q_bf, fc, fs);
  rope_k_dual<<<1024, 256, 0, stream>>>(cache_k, k_bf, fc, fs);
  transpose_v<<<dim3(32, 2, 8), 256, 0, stream>>>(cache_v, Vt);
  hipMemsetAsync(cache_k + (size_t)2048 * 1024, 0, (size_t)2048 * 1024 * 4, stream);
  hipMemsetAsync(cache_v + (size_t)2048 * 1024, 0, (size_t)2048 * 1024 * 4, stream);

  // attention: 1024 blocks x 2 waves (KV-parity split, in-block merge)
  attn_fwd4<<<1024, 128, 0, stream>>>(q_bf, k_bf, Vt, attn_out);

  // output projection
  cvt_bf16<<<8192, 256, 0, stream>>>(wo, slotA);
  gemm_bf<<<dim3(32, 16), 256, 0, stream>>>(attn_out, slotA, out_main, out_main, 4096, 4096, 1 << 30);
}

// Round 12
// 452.229 us; speedup vs baseline: 1.0897x; 1.0897x over previous
//
#include <hip/hip_runtime.h>
#include <hip/hip_bf16.h>

// Device buffers are FLOAT32 (confirmed R4/R5). bf16 MFMA compute, f32 accum.
// R11->R12: R11's launch_bounds(128,2) spilled ~120 regs (VGPR 248->128,
// WRITE_SIZE 16->40MB) -> reverted. New: attention K/V tiles staged into LDS
// cooperatively by 4 waves (=4 heads of one kvh) with pre-swizzled-source
// global_load_lds (m173) + XOR-swizzled ds_read_b128 frags (T2). Cuts vmem
// instrs 4x + shares them; compute math bit-identical to R10.

typedef __attribute__((ext_vector_type(8))) short short8_t;
typedef __attribute__((ext_vector_type(2))) unsigned uint2_t;
typedef __attribute__((ext_vector_type(8))) __bf16 bf16x8;
typedef __attribute__((ext_vector_type(4))) float f32x4;
typedef __attribute__((ext_vector_type(16))) float f32x16;

#define SEQLEN 2048
#define QSCALE 0.08838834764831845f   // HEAD_DIM^-0.5, folded into Q at RoPE

__device__ __forceinline__ short f2b(float f) {
  if (!__builtin_isfinite(f)) f = 0.0f;   // diagnostic scrub (final stores only)
  union { float f; unsigned u; } v; v.f = f;
  unsigned r = (v.u + 0x7fffu + ((v.u >> 16) & 1u)) >> 16;  // RNE
  return (short)r;
}
__device__ __forceinline__ float sf(float f) {
  return __builtin_isfinite(f) ? f : 0.0f;
}
__device__ __forceinline__ short8_t cvt8(const float* p) {
  f32x4 a = *(const f32x4*)p;
  f32x4 b = *(const f32x4*)(p + 4);
  short8_t o;
  o[0] = f2b(a[0]); o[1] = f2b(a[1]); o[2] = f2b(a[2]); o[3] = f2b(a[3]);
  o[4] = f2b(b[0]); o[5] = f2b(b[1]); o[6] = f2b(b[2]); o[7] = f2b(b[3]);
  return o;
}
// pack two f32 -> (bf16 hi<<16 | bf16 lo); inputs finite by construction
__device__ __forceinline__ unsigned pkb(float lo, float hi) {
  union { float f; unsigned u; } a, b; a.f = lo; b.f = hi;
  unsigned ra = (a.u + 0x7fffu + ((a.u >> 16) & 1u)) >> 16;
  unsigned rb = (b.u + 0x7fffu + ((b.u >> 16) & 1u)) & 0xffff0000u;
  return rb | ra;
}

#define GLD16(gp, lp) __builtin_amdgcn_global_load_lds( \
    (const __attribute__((address_space(1))) void*)(gp), \
    (__attribute__((address_space(3))) void*)(lp), 16, 0, 0)

// ---------------------------------------------------------------------------
__global__ __launch_bounds__(256) void cvt_bf16(
    const float* __restrict__ in, short* __restrict__ out)
{
  size_t i = ((size_t)blockIdx.x * 256 + threadIdx.x) * 8;
  *(short8_t*)&out[i] = cvt8(in + i);
}

// ---------------------------------------------------------------------------
// GEMM: C[m][n] = sum_k A[m][k]*W[n][k], A/W bf16, C f32. m97 structure.
// ---------------------------------------------------------------------------
__global__ __launch_bounds__(256) void gemm_bf(
    const short* __restrict__ A, const short* __restrict__ W,
    float* __restrict__ C1, float* __restrict__ C2,
    int K, int ldc, int splitN)
{
  __shared__ short As[128 * 64];
  __shared__ short Ws[128 * 64];
  const int tid  = threadIdx.x;
  const int lane = tid & 63;
  const int wid  = tid >> 6;
  const int l15  = lane & 15;
  const int l4   = lane >> 4;

  const int nwg = (int)(gridDim.x * gridDim.y);
  int bid = (int)(blockIdx.y * gridDim.x + blockIdx.x);
  int swz = (bid & 7) * (nwg >> 3) + (bid >> 3);
  const int m0 = (swz / (int)gridDim.x) * 128;
  const int n0 = (swz % (int)gridDim.x) * 128;

  const int wr = (wid >> 1) * 64;
  const int wc = (wid & 1) * 64;
  const int srow = tid >> 3;
  const int scol = (tid & 7) * 8;

  f32x4 acc[4][4] = {};

  const short* Ab = A + (size_t)(m0 + srow) * K + scol;
  const short* Wb = W + (size_t)(n0 + srow) * K + scol;

  for (int k0 = 0; k0 < K; k0 += 64) {
#pragma unroll
    for (int i = 0; i < 4; ++i) {
      GLD16(Ab + (size_t)(i * 32) * K + k0, &As[(i * 32 + wid * 8) * 64]);
      GLD16(Wb + (size_t)(i * 32) * K + k0, &Ws[(i * 32 + wid * 8) * 64]);
    }
    __syncthreads();

#pragma unroll
    for (int kk = 0; kk < 2; ++kk) {
      bf16x8 af[4], wf[4];
#pragma unroll
      for (int m = 0; m < 4; ++m)
        af[m] = *(const bf16x8*)&As[(wr + m * 16 + l15) * 64 + kk * 32 + l4 * 8];
#pragma unroll
      for (int n = 0; n < 4; ++n)
        wf[n] = *(const bf16x8*)&Ws[(wc + n * 16 + l15) * 64 + kk * 32 + l4 * 8];
#pragma unroll
      for (int m = 0; m < 4; ++m)
#pragma unroll
        for (int n = 0; n < 4; ++n)
          acc[m][n] = __builtin_amdgcn_mfma_f32_16x16x32_bf16(af[m], wf[n], acc[m][n], 0, 0, 0);
    }
    __syncthreads();
  }

  float* Cb = (n0 < splitN) ? C1 : (C2 - splitN);
#pragma unroll
  for (int m = 0; m < 4; ++m) {
    int rbase = m0 + wr + m * 16 + l4 * 4;
#pragma unroll
    for (int n = 0; n < 4; ++n) {
      int cbase = n0 + wc + n * 16 + l15;
#pragma unroll
      for (int r = 0; r < 4; ++r)
        Cb[(size_t)(rbase + r) * ldc + cbase] = sf(acc[m][n][r]);
    }
  }
}

// ---------------------------------------------------------------------------
// RoPE
// ---------------------------------------------------------------------------
__device__ __forceinline__ void rope8(const float* in, float* out,
                                      const float* fc, const float* fs, int t, int p0)
{
  f32x4 a = *(const f32x4*)in;
  f32x4 b = *(const f32x4*)(in + 4);
  f32x4 cv = *(const f32x4*)&fc[t * 64 + p0];
  f32x4 sv = *(const f32x4*)&fs[t * 64 + p0];
  float x0[8] = {a[0], a[1], a[2], a[3], b[0], b[1], b[2], b[3]};
#pragma unroll
  for (int i = 0; i < 4; ++i) {
    float xr = x0[2 * i], xi = x0[2 * i + 1];
    out[2 * i]     = sf(xr * cv[i] - xi * sv[i]);
    out[2 * i + 1] = sf(xr * sv[i] + xi * cv[i]);
  }
}

__global__ __launch_bounds__(256) void rope_q_bf(
    const float* __restrict__ q, short* __restrict__ qb,
    const float* __restrict__ fc, const float* __restrict__ fs)
{
  size_t idx = ((size_t)blockIdx.x * 256 + threadIdx.x) * 8;
  int t   = (int)(idx >> 12);
  int col = (int)(idx & 4095);
  float o[8];
  rope8(&q[idx], o, fc, fs, t, (col & 127) >> 1);
  short8_t ob;
#pragma unroll
  for (int i = 0; i < 8; ++i) ob[i] = f2b(o[i] * QSCALE);
  *(short8_t*)&qb[idx] = ob;
}

__global__ __launch_bounds__(256) void rope_k_dual(
    float* __restrict__ ck, short* __restrict__ kb,
    const float* __restrict__ fc, const float* __restrict__ fs)
{
  size_t idx = ((size_t)blockIdx.x * 256 + threadIdx.x) * 8;
  int t   = (int)(idx >> 10);
  int col = (int)(idx & 1023);
  float o[8];
  rope8(&ck[idx], o, fc, fs, t, (col & 127) >> 1);
  *(f32x4*)&ck[idx]     = f32x4{o[0], o[1], o[2], o[3]};
  *(f32x4*)&ck[idx + 4] = f32x4{o[4], o[5], o[6], o[7]};
  short8_t ob;
#pragma unroll
  for (int i = 0; i < 8; ++i) ob[i] = f2b(o[i]);
  *(short8_t*)&kb[idx] = ob;
}

// cache_v f32 [2048][8*128] -> Vt bf16 [8][128][2048]
__global__ __launch_bounds__(256) void transpose_v(
    const float* __restrict__ cv, short* __restrict__ Vt)
{
  __shared__ short tile[64][72];
  const int t0 = blockIdx.x * 64;
  const int d0 = blockIdx.y * 64;
  const int h  = blockIdx.z;
  const int tid = threadIdx.x;
  const int r = tid >> 3;
  const int c = (tid & 7) * 8;
#pragma unroll
  for (int it = 0; it < 2; ++it) {
    short8_t v = cvt8(&cv[(size_t)(t0 + it * 32 + r) * 1024 + h * 128 + d0 + c]);
    *(short8_t*)&tile[it * 32 + r][c] = v;
  }
  __syncthreads();
#pragma unroll
  for (int it = 0; it < 2; ++it) {
    int dr = it * 32 + r;
    short8_t v;
#pragma unroll
    for (int i = 0; i < 8; ++i) v[i] = tile[c + i][dr];
    *(short8_t*)&Vt[(size_t)(h * 128 + d0 + dr) * SEQLEN + t0 + c] = v;
  }
}

// ---------------------------------------------------------------------------
// Causal flash attention, swapped-QK^T 32x32, LDS-staged K/V tiles.
// Grid 256 (bid&7 = kvh XCD pin, i = bid>>3), 4 waves/block = 4 heads.
// Each wave: q-tiles A=63-i (heavy) + B=i (light), sharing staged K/V.
// Staging: global_load_lds with pre-swizzled source (chunk ^= row&mask),
// frag ds_read_b128 applies the same XOR -> <=4-way bank conflicts.
// Lane state: q = lane&31, S^T keys = crow(r,hi) = (r&3)+8*(r>>2)+4*hi.
// ---------------------------------------------------------------------------
__global__ __launch_bounds__(256) void attn_fwd5(
    const short* __restrict__ Q,    // [2048][4096] bf16, pre-scaled
    const short* __restrict__ Kc,   // [2048][1024] bf16
    const short* __restrict__ Vt,   // [8][128][2048] bf16
    short* __restrict__ O)          // [2048][4096] bf16
{
  const int bid = (int)blockIdx.x;
  const int kvh = bid & 7;
  const int i   = bid >> 3;             // 0..31
  const int qtA = 63 - i, qtB = i;
  const int tid = (int)threadIdx.x;
  const int wid = tid >> 6;             // wave = head slot
  const int h   = kvh * 4 + wid;
  const int lane = tid & 63;
  const int l31 = lane & 31;
  const int hi  = lane >> 5;

  __shared__ short Ks[64 * 128];        // [row][chunk*8], chunks XOR row&15
  __shared__ short Vs[128 * 64];        // [d][chunk*8],   chunks XOR row&7
  __shared__ short PA[4][32][72], PB[4][32][72];
  __shared__ float exch[4][64];

  const int q0A = qtA * 32, q0B = qtB * 32;
  const int qgA = q0A + l31, qgB = q0B + l31;
  const int kendA = q0A + 32, kendB = q0B + 32;

  bf16x8 qfA[8], qfB[8];
  {
    const short* qpA = Q + (size_t)qgA * 4096 + h * 128 + hi * 8;
    const short* qpB = Q + (size_t)qgB * 4096 + h * 128 + hi * 8;
#pragma unroll
    for (int ks = 0; ks < 8; ++ks) {
      qfA[ks] = *(const bf16x8*)(qpA + ks * 16);
      qfB[ks] = *(const bf16x8*)(qpB + ks * 16);
    }
  }

  f32x16 oA0 = {}, oA1 = {}, oA2 = {}, oA3 = {};
  f32x16 oB0 = {}, oB1 = {}, oB2 = {}, oB3 = {};
  float mA = -1e30f, lA = 0.f, mB = -1e30f, lB = 0.f;

  // staging lane constants
  const int krow_base = wid * 16;       // this wave's K rows (16)
  const int vrow_base = wid * 32;       // this wave's V rows (32)

  for (int kt = 0; kt < kendA; kt += 64) {
    // ---- stage K tile [64][128] and V tile [128][64] (all 4 waves) ----
#pragma unroll
    for (int it = 0; it < 4; ++it) {
      int krow = krow_base + it * 4 + (lane >> 4);
      int kchp = lane & 15;
      int kgch = kchp ^ (krow & 15);
      GLD16(Kc + (size_t)(kt + krow) * 1024 + kvh * 128 + kgch * 8,
            &Ks[wid * 2048 + it * 512]);
      int vrow = vrow_base + it * 8 + (lane >> 3);
      int vchp = lane & 7;
      int vgch = vchp ^ (vrow & 7);
      GLD16(Vt + (size_t)(kvh * 128 + vrow) * SEQLEN + kt + vgch * 8,
            &Vs[wid * 2048 + it * 512]);
    }
    __syncthreads();   // staging complete (vmcnt drained)

    const bool actB = (kt < kendB);     // wave-uniform
    f32x16 sA0 = {}, sA1 = {}, sB0 = {}, sB1 = {};
    {
      const int xk = l31 & 15;
      __builtin_amdgcn_s_setprio(1);
#pragma unroll
      for (int ks = 0; ks < 8; ++ks) {
        int ch = (ks * 2 + hi) ^ xk;
        bf16x8 k0 = *(const bf16x8*)&Ks[l31 * 128 + ch * 8];
        bf16x8 k1 = *(const bf16x8*)&Ks[(32 + l31) * 128 + ch * 8];
        sA0 = __builtin_amdgcn_mfma_f32_32x32x16_bf16(k0, qfA[ks], sA0, 0, 0, 0);
        sA1 = __builtin_amdgcn_mfma_f32_32x32x16_bf16(k1, qfA[ks], sA1, 0, 0, 0);
        if (actB) {
          sB0 = __builtin_amdgcn_mfma_f32_32x32x16_bf16(k0, qfB[ks], sB0, 0, 0, 0);
          sB1 = __builtin_amdgcn_mfma_f32_32x32x16_bf16(k1, qfB[ks], sB1, 0, 0, 0);
        }
      }
      __builtin_amdgcn_s_setprio(0);
    }

    // ----- tile A softmax -----
    if (kt + 63 > q0A) {
#pragma unroll
      for (int r = 0; r < 16; ++r) {
        int crow = (r & 3) + 8 * (r >> 2) + 4 * hi;
        if (kt + crow > qgA)      sA0[r] = -1e30f;
        if (kt + 32 + crow > qgA) sA1[r] = -1e30f;
      }
    }
    {
      float t[8];
#pragma unroll
      for (int r = 0; r < 8; ++r)
        t[r] = fmaxf(fmaxf(sA0[r], sA0[r + 8]), fmaxf(sA1[r], sA1[r + 8]));
      float pmax = fmaxf(fmaxf(fmaxf(t[0], t[1]), fmaxf(t[2], t[3])),
                         fmaxf(fmaxf(t[4], t[5]), fmaxf(t[6], t[7])));
      pmax = fmaxf(pmax, __shfl_xor(pmax, 32, 64));
      if (!__all(pmax <= mA + 8.f)) {
        float mnew = fmaxf(mA, pmax);
        float resc = __expf(mA - mnew);
        mA = mnew; lA *= resc;
        if (lane < 32) exch[wid][l31] = resc;
#pragma unroll
        for (int r = 0; r < 16; ++r) {
          float rs = exch[wid][(r & 3) + 8 * (r >> 2) + 4 * hi];
          oA0[r] *= rs; oA1[r] *= rs; oA2[r] *= rs; oA3[r] *= rs;
        }
      }
      float psum = 0.f;
#pragma unroll
      for (int r = 0; r < 16; ++r) { sA0[r] = __expf(sA0[r] - mA); psum += sA0[r]; }
#pragma unroll
      for (int r = 0; r < 16; ++r) { sA1[r] = __expf(sA1[r] - mA); psum += sA1[r]; }
      lA += psum + __shfl_xor(psum, 32, 64);
#pragma unroll
      for (int t4 = 0; t4 < 4; ++t4) {
        int c = 8 * t4 + 4 * hi;
        *(uint2_t*)&PA[wid][l31][c]      = uint2_t{pkb(sA0[4*t4], sA0[4*t4+1]), pkb(sA0[4*t4+2], sA0[4*t4+3])};
        *(uint2_t*)&PA[wid][l31][32 + c] = uint2_t{pkb(sA1[4*t4], sA1[4*t4+1]), pkb(sA1[4*t4+2], sA1[4*t4+3])};
      }
    }

    // ----- tile B softmax -----
    if (actB) {
      if (kt + 63 > q0B) {
#pragma unroll
        for (int r = 0; r < 16; ++r) {
          int crow = (r & 3) + 8 * (r >> 2) + 4 * hi;
          if (kt + crow > qgB)      sB0[r] = -1e30f;
          if (kt + 32 + crow > qgB) sB1[r] = -1e30f;
        }
      }
      float t[8];
#pragma unroll
      for (int r = 0; r < 8; ++r)
        t[r] = fmaxf(fmaxf(sB0[r], sB0[r + 8]), fmaxf(sB1[r], sB1[r + 8]));
      float pmax = fmaxf(fmaxf(fmaxf(t[0], t[1]), fmaxf(t[2], t[3])),
                         fmaxf(fmaxf(t[4], t[5]), fmaxf(t[6], t[7])));
      pmax = fmaxf(pmax, __shfl_xor(pmax, 32, 64));
      if (!__all(pmax <= mB + 8.f)) {
        float mnew = fmaxf(mB, pmax);
        float resc = __expf(mB - mnew);
        mB = mnew; lB *= resc;
        if (lane < 32) exch[wid][32 + l31] = resc;
#pragma unroll
        for (int r = 0; r < 16; ++r) {
          float rs = exch[wid][32 + (r & 3) + 8 * (r >> 2) + 4 * hi];
          oB0[r] *= rs; oB1[r] *= rs; oB2[r] *= rs; oB3[r] *= rs;
        }
      }
      float psum = 0.f;
#pragma unroll
      for (int r = 0; r < 16; ++r) { sB0[r] = __expf(sB0[r] - mB); psum += sB0[r]; }
#pragma unroll
      for (int r = 0; r < 16; ++r) { sB1[r] = __expf(sB1[r] - mB); psum += sB1[r]; }
      lB += psum + __shfl_xor(psum, 32, 64);
#pragma unroll
      for (int t4 = 0; t4 < 4; ++t4) {
        int c = 8 * t4 + 4 * hi;
        *(uint2_t*)&PB[wid][l31][c]      = uint2_t{pkb(sB0[4*t4], sB0[4*t4+1]), pkb(sB0[4*t4+2], sB0[4*t4+3])};
        *(uint2_t*)&PB[wid][l31][32 + c] = uint2_t{pkb(sB1[4*t4], sB1[4*t4+1]), pkb(sB1[4*t4+2], sB1[4*t4+3])};
      }
    }

    // ----- PV (V-frags from LDS, shared by A and B) -----
    {
      const int xv = l31 & 7;
#pragma unroll
      for (int g = 0; g < 4; ++g) {
        int ch = (g * 2 + hi) ^ xv;
        bf16x8 vf0 = *(const bf16x8*)&Vs[(l31)       * 64 + ch * 8];
        bf16x8 vf1 = *(const bf16x8*)&Vs[(32 + l31)  * 64 + ch * 8];
        bf16x8 vf2 = *(const bf16x8*)&Vs[(64 + l31)  * 64 + ch * 8];
        bf16x8 vf3 = *(const bf16x8*)&Vs[(96 + l31)  * 64 + ch * 8];
        bf16x8 pfA = *(const bf16x8*)&PA[wid][l31][g * 16 + hi * 8];
        __builtin_amdgcn_s_setprio(1);
        oA0 = __builtin_amdgcn_mfma_f32_32x32x16_bf16(pfA, vf0, oA0, 0, 0, 0);
        oA1 = __builtin_amdgcn_mfma_f32_32x32x16_bf16(pfA, vf1, oA1, 0, 0, 0);
        oA2 = __builtin_amdgcn_mfma_f32_32x32x16_bf16(pfA, vf2, oA2, 0, 0, 0);
        oA3 = __builtin_amdgcn_mfma_f32_32x32x16_bf16(pfA, vf3, oA3, 0, 0, 0);
        if (actB) {
          bf16x8 pfB = *(const bf16x8*)&PB[wid][l31][g * 16 + hi * 8];
          oB0 = __builtin_amdgcn_mfma_f32_32x32x16_bf16(pfB, vf0, oB0, 0, 0, 0);
          oB1 = __builtin_amdgcn_mfma_f32_32x32x16_bf16(pfB, vf1, oB1, 0, 0, 0);
          oB2 = __builtin_amdgcn_mfma_f32_32x32x16_bf16(pfB, vf2, oB2, 0, 0, 0);
          oB3 = __builtin_amdgcn_mfma_f32_32x32x16_bf16(pfB, vf3, oB3, 0, 0, 0);
        }
        __builtin_amdgcn_s_setprio(0);
      }
    }
    __syncthreads();   // all waves done reading Ks/Vs before next stage
  }

  // normalize + store (A and B)
  if (lane < 32) { exch[wid][l31] = 1.f / lA; exch[wid][32 + l31] = 1.f / lB; }
#pragma unroll
  for (int r = 0; r < 16; ++r) {
    int crow = (r & 3) + 8 * (r >> 2) + 4 * hi;
    float invA = exch[wid][crow];
    float invB = exch[wid][32 + crow];
    short* obA = O + (size_t)(q0A + crow) * 4096 + h * 128 + l31;
    short* obB = O + (size_t)(q0B + crow) * 4096 + h * 128 + l31;
    obA[0]  = f2b(oA0[r] * invA);
    obA[32] = f2b(oA1[r] * invA);
    obA[64] = f2b(oA2[r] * invA);
    obA[96] = f2b(oA3[r] * invA);
    obB[0]  = f2b(oB0[r] * invB);
    obB[32] = f2b(oB1[r] * invB);
    obB[64] = f2b(oB2[r] * invB);
    obB[96] = f2b(oB3[r] * invB);
  }
}

// ---------------------------------------------------------------------------
extern "C" void kernel_launch(void* const* d_in, const int* in_sizes, int n_in,
                              void* d_out, int out_size, void* d_ws, size_t ws_size,
                              hipStream_t stream) {
  const float* x  = (const float*)d_in[0];
  const float* wq = (const float*)d_in[1];
  const float* wk = (const float*)d_in[2];
  const float* wv = (const float*)d_in[3];
  const float* wo = (const float*)d_in[4];
  const float* fc = (const float*)d_in[5];
  const float* fs = (const float*)d_in[6];

  float* out = (float*)d_out;
  float* out_main = out;                               // [2048][4096]
  float* cache_k  = out + (size_t)2048 * 4096;         // [4096][8][128]
  float* cache_v  = cache_k + (size_t)4096 * 8 * 128;  // [4096][8][128]

  const size_t MB_W = 33554432;   // 4096x4096 bf16
  const size_t MB_X = 16777216;   // 2048x4096 bf16
  short* slotA = (short*)d_ws;
  short* x_bf  = (short*)((char*)d_ws + MB_W);
  short* attn_out = x_bf;
  short* Vt    = (short*)((char*)d_ws + MB_W + MB_X);
  short* q_bf  = slotA;
  short* k_bf  = slotA + (size_t)2048 * 4096;

  // converts + projections
  cvt_bf16<<<4096, 256, 0, stream>>>(x, x_bf);
  cvt_bf16<<<8192, 256, 0, stream>>>(wq, slotA);
  gemm_bf<<<dim3(32, 16), 256, 0, stream>>>(x_bf, slotA, out_main, out_main, 4096, 4096, 1 << 30);
  cvt_bf16<<<2048, 256, 0, stream>>>(wk, slotA);
  cvt_bf16<<<2048, 256, 0, stream>>>(wv, slotA + (size_t)1024 * 4096);
  gemm_bf<<<dim3(16, 16), 256, 0, stream>>>(x_bf, slotA, cache_k, cache_v, 4096, 1024, 1024);

  // RoPE + V transpose + cache tail zeros
  rope_q_bf<<<4096, 256, 0, stream>>>(out_main, q_bf, fc, fs);
  rope_k_dual<<<1024, 256, 0, stream>>>(cache_k, k_bf, fc, fs);
  transpose_v<<<dim3(32, 2, 8), 256, 0, stream>>>(cache_v, Vt);
  hipMemsetAsync(cache_k + (size_t)2048 * 1024, 0, (size_t)2048 * 1024 * 4, stream);
  hipMemsetAsync(cache_v + (size_t)2048 * 1024, 0, (size_t)2048 * 1024 * 4, stream);

  // attention: 256 blocks x 4 waves (4 heads/kvh), LDS-staged K/V
  attn_fwd5<<<256, 256, 0, stream>>>(q_bf, k_bf, Vt, attn_out);

  // output projection
  cvt_bf16<<<8192, 256, 0, stream>>>(wo, slotA);
  gemm_bf<<<dim3(32, 16), 256, 0, stream>>>(attn_out, slotA, out_main, out_main, 4096, 4096, 1 << 30);
}